// Round 1
// baseline (5616.441 us; speedup 1.0000x reference)
//
#include <hip/hip_runtime.h>
#include <math.h>

// SimilarityModel: fused attention-segmentation head.
// Key algebraic simplification: seg = attn @ (V @ conv_w^T) -> scalar v per token.
// N = 12544 tokens, D = 1024. All fp32 (round-0 correctness baseline).

#define DD 1024
#define NN 12544
#define NSPLIT 8
#define NTILES 98   // NN / 128

// ---------------------------------------------------------------------------
// u[k] = sum_d Wv[d,k] * cw[d]   (Wv row-major (D,D): Wv[d*DD+k])
// block 0 also reduces c = sum_d bv[d]*cw[d]
__global__ void k_u(const float* __restrict__ Wv, const float* __restrict__ cw,
                    const float* __restrict__ bv, float* __restrict__ u,
                    float* __restrict__ cptr) {
    int k = blockIdx.x * 256 + threadIdx.x;
    float acc = 0.f;
#pragma unroll 8
    for (int d = 0; d < DD; ++d) acc += Wv[(size_t)d * DD + k] * cw[d];
    u[k] = acc;
    if (blockIdx.x == 0) {
        __shared__ float red[256];
        float ca = 0.f;
        for (int d = threadIdx.x; d < DD; d += 256) ca += bv[d] * cw[d];
        red[threadIdx.x] = ca;
        __syncthreads();
        for (int s = 128; s > 0; s >>= 1) {
            if (threadIdx.x < s) red[threadIdx.x] += red[threadIdx.x + s];
            __syncthreads();
        }
        if (threadIdx.x == 0) cptr[0] = red[0];
    }
}

// ---------------------------------------------------------------------------
// vsc[n] = c + sum_k rf[k*NN+n] * u[k]
__global__ void k_vsc(const float* __restrict__ rf, const float* __restrict__ u,
                      const float* __restrict__ cptr, float* __restrict__ vsc) {
    int n = blockIdx.x * 256 + threadIdx.x;
    float acc = cptr[0];
#pragma unroll 8
    for (int k = 0; k < DD; ++k) acc += rf[(size_t)k * NN + n] * u[k];
    vsc[n] = acc;
}

// ---------------------------------------------------------------------------
// Projection GEMM: out[d',n] = scale * ( sum_d W[d',d]*(rf[d,n] + pe?) + bias[d'] )
// M=1024 (d'), N'=12544 (tokens), K=1024. BM=BN=128, KB=32, 256 thr, 8x8/thread.
template <bool ADD_PE>
__global__ __launch_bounds__(256, 2)
void k_proj(const float* __restrict__ W, const float* __restrict__ bias,
            const float* __restrict__ rf, const int* __restrict__ sig,
            const float* __restrict__ pe, float* __restrict__ out, float scale) {
    __shared__ float lds_w[32][132];
    __shared__ float lds_x[32][132];
    __shared__ int sig_l[128];
    const int t = threadIdx.x;
    const int n0 = blockIdx.x * 128;
    const int m0 = blockIdx.y * 128;
    if (ADD_PE && t < 128) sig_l[t] = sig[n0 + t];
    const int tm = t >> 4, tn = t & 15;
    float acc[8][8] = {};
    for (int kk = 0; kk < DD; kk += 32) {
        __syncthreads();
        // stage W tile transposed: lds_w[k][m] = W[(m0+m)*DD + kk+k]
#pragma unroll
        for (int i = 0; i < 4; ++i) {
            int idx = t + i * 256;
            int row = idx >> 3, kq = idx & 7;
            const float4 w = *(const float4*)&W[(size_t)(m0 + row) * DD + kk + kq * 4];
            lds_w[kq * 4 + 0][row] = w.x;
            lds_w[kq * 4 + 1][row] = w.y;
            lds_w[kq * 4 + 2][row] = w.z;
            lds_w[kq * 4 + 3][row] = w.w;
        }
        // stage X tile: lds_x[k][n] = rf[(kk+k)*NN + n0+n] (+ patch_embed gather)
#pragma unroll
        for (int i = 0; i < 4; ++i) {
            int idx = t + i * 256;
            int k = idx >> 5, nf = idx & 31;
            float4 x = *(const float4*)&rf[(size_t)(kk + k) * NN + n0 + nf * 4];
            if (ADD_PE) {
                x.x += pe[sig_l[nf * 4 + 0] * DD + kk + k];
                x.y += pe[sig_l[nf * 4 + 1] * DD + kk + k];
                x.z += pe[sig_l[nf * 4 + 2] * DD + kk + k];
                x.w += pe[sig_l[nf * 4 + 3] * DD + kk + k];
            }
            *(float4*)&lds_x[k][nf * 4] = x;
        }
        __syncthreads();
#pragma unroll 8
        for (int k = 0; k < 32; ++k) {
            float a[8], b[8];
            *(float4*)&a[0] = *(const float4*)&lds_w[k][tm * 8];
            *(float4*)&a[4] = *(const float4*)&lds_w[k][tm * 8 + 4];
            *(float4*)&b[0] = *(const float4*)&lds_x[k][tn * 8];
            *(float4*)&b[4] = *(const float4*)&lds_x[k][tn * 8 + 4];
#pragma unroll
            for (int i = 0; i < 8; ++i)
#pragma unroll
                for (int j = 0; j < 8; ++j) acc[i][j] += a[i] * b[j];
        }
    }
#pragma unroll
    for (int i = 0; i < 8; ++i) {
        int gm = m0 + tm * 8 + i;
        float bb = bias[gm];
        float4 o0, o1;
        o0.x = (acc[i][0] + bb) * scale;
        o0.y = (acc[i][1] + bb) * scale;
        o0.z = (acc[i][2] + bb) * scale;
        o0.w = (acc[i][3] + bb) * scale;
        o1.x = (acc[i][4] + bb) * scale;
        o1.y = (acc[i][5] + bb) * scale;
        o1.z = (acc[i][6] + bb) * scale;
        o1.w = (acc[i][7] + bb) * scale;
        *(float4*)&out[(size_t)gm * NN + n0 + tn * 8] = o0;
        *(float4*)&out[(size_t)gm * NN + n0 + tn * 8 + 4] = o1;
    }
}

// ---------------------------------------------------------------------------
// Fused scores + online softmax + weighted scalar-V sum.
// scores[i,j] = sum_d qt[d,i]*kt[d,j]  (scale pre-folded into qt).
// grid.x = row tile (98), grid.y = column split (8). Partials (m,l,a) to ws.
__global__ __launch_bounds__(256, 2)
void k_attn(const float* __restrict__ qt, const float* __restrict__ kt,
            const float* __restrict__ vsc, float* __restrict__ pm,
            float* __restrict__ pl, float* __restrict__ pa) {
    __shared__ float lds_q[32][132];
    __shared__ float lds_k[32][132];
    const int t = threadIdx.x;
    const int m0 = blockIdx.x * 128;
    const int split = blockIdx.y;
    const int tm = t >> 4, tn = t & 15;
    float rm[8], rl[8], ra[8];
#pragma unroll
    for (int i = 0; i < 8; ++i) { rm[i] = -INFINITY; rl[i] = 0.f; ra[i] = 0.f; }

    for (int nt = split; nt < NTILES; nt += NSPLIT) {
        const int n0 = nt * 128;
        float s[8][8] = {};
        for (int kk = 0; kk < DD; kk += 32) {
            __syncthreads();
#pragma unroll
            for (int i = 0; i < 4; ++i) {
                int idx = t + i * 256;
                int k = idx >> 5, nf = idx & 31;
                *(float4*)&lds_q[k][nf * 4] =
                    *(const float4*)&qt[(size_t)(kk + k) * NN + m0 + nf * 4];
                *(float4*)&lds_k[k][nf * 4] =
                    *(const float4*)&kt[(size_t)(kk + k) * NN + n0 + nf * 4];
            }
            __syncthreads();
#pragma unroll 8
            for (int k = 0; k < 32; ++k) {
                float a[8], b[8];
                *(float4*)&a[0] = *(const float4*)&lds_q[k][tm * 8];
                *(float4*)&a[4] = *(const float4*)&lds_q[k][tm * 8 + 4];
                *(float4*)&b[0] = *(const float4*)&lds_k[k][tn * 8];
                *(float4*)&b[4] = *(const float4*)&lds_k[k][tn * 8 + 4];
#pragma unroll
                for (int i = 0; i < 8; ++i)
#pragma unroll
                    for (int j = 0; j < 8; ++j) s[i][j] += a[i] * b[j];
            }
        }
        // online softmax update (rows owned by 16-lane groups sharing tm)
        float vcol[8];
        *(float4*)&vcol[0] = *(const float4*)&vsc[n0 + tn * 8];
        *(float4*)&vcol[4] = *(const float4*)&vsc[n0 + tn * 8 + 4];
#pragma unroll
        for (int i = 0; i < 8; ++i) {
            float mx = s[i][0];
#pragma unroll
            for (int j = 1; j < 8; ++j) mx = fmaxf(mx, s[i][j]);
            for (int off = 1; off < 16; off <<= 1) mx = fmaxf(mx, __shfl_xor(mx, off));
            const float mnew = fmaxf(rm[i], mx);
            float sp = 0.f, spv = 0.f;
#pragma unroll
            for (int j = 0; j < 8; ++j) {
                float p = __expf(s[i][j] - mnew);
                sp += p;
                spv += p * vcol[j];
            }
            for (int off = 1; off < 16; off <<= 1) {
                sp += __shfl_xor(sp, off);
                spv += __shfl_xor(spv, off);
            }
            const float f = __expf(rm[i] - mnew);
            rl[i] = rl[i] * f + sp;
            ra[i] = ra[i] * f + spv;
            rm[i] = mnew;
        }
    }
    if (tn == 0) {
#pragma unroll
        for (int i = 0; i < 8; ++i) {
            int row = m0 + tm * 8 + i;
            pm[(size_t)split * NN + row] = rm[i];
            pl[(size_t)split * NN + row] = rl[i];
            pa[(size_t)split * NN + row] = ra[i];
        }
    }
}

// ---------------------------------------------------------------------------
// Merge column-split partials, apply head bias + sigmoid.
__global__ void k_comb(const float* __restrict__ pm, const float* __restrict__ pl,
                       const float* __restrict__ pa, const float* __restrict__ cb,
                       float* __restrict__ out) {
    int n = blockIdx.x * 256 + threadIdx.x;
    float gm = -INFINITY;
#pragma unroll
    for (int s = 0; s < NSPLIT; ++s) gm = fmaxf(gm, pm[(size_t)s * NN + n]);
    float l = 0.f, a = 0.f;
#pragma unroll
    for (int s = 0; s < NSPLIT; ++s) {
        float f = __expf(pm[(size_t)s * NN + n] - gm);
        l += pl[(size_t)s * NN + n] * f;
        a += pa[(size_t)s * NN + n] * f;
    }
    float x = a / l + cb[0];
    out[n] = 1.f / (1.f + __expf(-x));
}

// ---------------------------------------------------------------------------
extern "C" void kernel_launch(void* const* d_in, const int* in_sizes, int n_in,
                              void* d_out, int out_size, void* d_ws, size_t ws_size,
                              hipStream_t stream) {
    const int* sig = (const int*)d_in[0];    // roi_signal (1,1,112,112)
    const float* rf = (const float*)d_in[1]; // roi_features (1,1024,112,112)
    // d_in[2] roi_mask: unused by the reference math
    const float* pe = (const float*)d_in[3]; // patch_embed (5,1024)
    const float* Wq = (const float*)d_in[4];
    const float* bq = (const float*)d_in[5];
    const float* Wk = (const float*)d_in[6];
    const float* bk = (const float*)d_in[7];
    const float* Wv = (const float*)d_in[8];
    const float* bv = (const float*)d_in[9];
    const float* cw = (const float*)d_in[10]; // conv_w (1,1024)
    const float* cb = (const float*)d_in[11]; // conv_b (1,)
    float* out = (float*)d_out;

    float* ws = (float*)d_ws;
    float* qt = ws;                                 // D*N
    float* kt = qt + (size_t)DD * NN;               // D*N
    float* u = kt + (size_t)DD * NN;                // 1024
    float* cptr = u + 1024;                         // 16 reserved (alignment)
    float* vsc = u + 1024 + 16;                     // N
    float* pm = vsc + NN;                           // NSPLIT*N
    float* pl = pm + (size_t)NSPLIT * NN;
    float* pa = pl + (size_t)NSPLIT * NN;

    k_u<<<DD / 256, 256, 0, stream>>>(Wv, cw, bv, u, cptr);
    k_vsc<<<NN / 256, 256, 0, stream>>>(rf, u, cptr, vsc);
    // scale 1/sqrt(1024) folded into Q
    k_proj<true><<<dim3(98, 8), 256, 0, stream>>>(Wq, bq, rf, sig, pe, qt, 0.03125f);
    k_proj<false><<<dim3(98, 8), 256, 0, stream>>>(Wk, bk, rf, sig, pe, kt, 1.0f);
    k_attn<<<dim3(98, NSPLIT), 256, 0, stream>>>(qt, kt, vsc, pm, pl, pa);
    k_comb<<<NN / 256, 256, 0, stream>>>(pm, pl, pa, cb, out);
}

// Round 2
// 1317.398 us; speedup vs baseline: 4.2633x; 4.2633x over previous
//
#include <hip/hip_runtime.h>
#include <math.h>

// SimilarityModel: seg = sigmoid( softmax(QK^T/32) @ v + cb ), v = scalar per token.
// Round 2: QK^T via bf16 MFMA (16x16x32), swizzled LDS, global_load_lds staging.

#define DD 1024
#define NN 12544
#define NSPLIT 10
#define NPART  20   // NSPLIT * 2 column-half waves
#define NTILES 98   // NN / 128

typedef __attribute__((ext_vector_type(8))) short short8;
typedef __attribute__((ext_vector_type(4))) float f32x4;
typedef unsigned short ushort_t;
typedef unsigned int uint32;

__device__ __forceinline__ ushort_t f2bf(float f) {
    union { float f; uint32 u; } v; v.f = f;
    uint32 u = v.u + 0x7FFF + ((v.u >> 16) & 1);   // RNE
    return (ushort_t)(u >> 16);
}

__device__ __forceinline__ void gload_lds16(const void* g, void* l) {
    __builtin_amdgcn_global_load_lds((const __attribute__((address_space(1))) uint32*)g,
                                     (__attribute__((address_space(3))) uint32*)l, 16, 0, 0);
}

// ---------------------------------------------------------------------------
// u[k] = sum_d Wv[d,k] * cw[d]; block 0 also reduces c = sum_d bv[d]*cw[d]
__global__ void k_u(const float* __restrict__ Wv, const float* __restrict__ cw,
                    const float* __restrict__ bv, float* __restrict__ u,
                    float* __restrict__ cptr) {
    int k = blockIdx.x * 256 + threadIdx.x;
    float acc = 0.f;
#pragma unroll 8
    for (int d = 0; d < DD; ++d) acc += Wv[(size_t)d * DD + k] * cw[d];
    u[k] = acc;
    if (blockIdx.x == 0) {
        __shared__ float red[256];
        float ca = 0.f;
        for (int d = threadIdx.x; d < DD; d += 256) ca += bv[d] * cw[d];
        red[threadIdx.x] = ca;
        __syncthreads();
        for (int s = 128; s > 0; s >>= 1) {
            if (threadIdx.x < s) red[threadIdx.x] += red[threadIdx.x + s];
            __syncthreads();
        }
        if (threadIdx.x == 0) cptr[0] = red[0];
    }
}

// ---------------------------------------------------------------------------
// vsc[n] = c + sum_k rf[k*NN+n] * u[k]
__global__ void k_vsc(const float* __restrict__ rf, const float* __restrict__ u,
                      const float* __restrict__ cptr, float* __restrict__ vsc) {
    int n = blockIdx.x * 256 + threadIdx.x;
    float acc = cptr[0];
#pragma unroll 8
    for (int k = 0; k < DD; ++k) acc += rf[(size_t)k * NN + n] * u[k];
    vsc[n] = acc;
}

// ---------------------------------------------------------------------------
// Projection GEMM (fp32 compute): out_bf16[n, d'] = bf16( scale*(W[d',:]@x[:,n] + b[d']) )
// Output layout token-major (N, D) for the attention kernel's staging.
template <bool ADD_PE>
__global__ __launch_bounds__(256, 2)
void k_proj(const float* __restrict__ W, const float* __restrict__ bias,
            const float* __restrict__ rf, const int* __restrict__ sig,
            const float* __restrict__ pe, ushort_t* __restrict__ out, float scale) {
    __shared__ float lds_w[32][132];
    __shared__ float lds_x[32][132];
    __shared__ int sig_l[128];
    const int t = threadIdx.x;
    const int n0 = blockIdx.x * 128;
    const int m0 = blockIdx.y * 128;
    if (ADD_PE && t < 128) sig_l[t] = sig[n0 + t];
    const int tm = t >> 4, tn = t & 15;
    float acc[8][8] = {};
    for (int kk = 0; kk < DD; kk += 32) {
        __syncthreads();
#pragma unroll
        for (int i = 0; i < 4; ++i) {
            int idx = t + i * 256;
            int row = idx >> 3, kq = idx & 7;
            const float4 w = *(const float4*)&W[(size_t)(m0 + row) * DD + kk + kq * 4];
            lds_w[kq * 4 + 0][row] = w.x;
            lds_w[kq * 4 + 1][row] = w.y;
            lds_w[kq * 4 + 2][row] = w.z;
            lds_w[kq * 4 + 3][row] = w.w;
        }
#pragma unroll
        for (int i = 0; i < 4; ++i) {
            int idx = t + i * 256;
            int k = idx >> 5, nf = idx & 31;
            float4 x = *(const float4*)&rf[(size_t)(kk + k) * NN + n0 + nf * 4];
            if (ADD_PE) {
                x.x += pe[sig_l[nf * 4 + 0] * DD + kk + k];
                x.y += pe[sig_l[nf * 4 + 1] * DD + kk + k];
                x.z += pe[sig_l[nf * 4 + 2] * DD + kk + k];
                x.w += pe[sig_l[nf * 4 + 3] * DD + kk + k];
            }
            *(float4*)&lds_x[k][nf * 4] = x;
        }
        __syncthreads();
#pragma unroll 8
        for (int k = 0; k < 32; ++k) {
            float a[8], b[8];
            *(float4*)&a[0] = *(const float4*)&lds_w[k][tm * 8];
            *(float4*)&a[4] = *(const float4*)&lds_w[k][tm * 8 + 4];
            *(float4*)&b[0] = *(const float4*)&lds_x[k][tn * 8];
            *(float4*)&b[4] = *(const float4*)&lds_x[k][tn * 8 + 4];
#pragma unroll
            for (int i = 0; i < 8; ++i)
#pragma unroll
                for (int j = 0; j < 8; ++j) acc[i][j] += a[i] * b[j];
        }
    }
    float bb[8];
#pragma unroll
    for (int i = 0; i < 8; ++i) bb[i] = bias[m0 + tm * 8 + i];
#pragma unroll
    for (int j = 0; j < 8; ++j) {
        int n = n0 + tn * 8 + j;
        short8 v;
#pragma unroll
        for (int i = 0; i < 8; ++i) v[i] = (short)f2bf((acc[i][j] + bb[i]) * scale);
        *(short8*)&out[(size_t)n * DD + m0 + tm * 8] = v;
    }
}

// ---------------------------------------------------------------------------
// Fused MFMA scores + online softmax + weighted scalar-V sum.
// qb/kb: bf16 (N, D). LDS tiles [128 tokens][64 k] with chunk-XOR swizzle
// (chunk ^= row&7), staged linearly via global_load_lds from pre-swizzled src.
__global__ __launch_bounds__(256, 2)
void k_attn(const ushort_t* __restrict__ qb, const ushort_t* __restrict__ kb,
            const float* __restrict__ vsc, float* __restrict__ pm,
            float* __restrict__ pl, float* __restrict__ pa) {
    __shared__ ushort_t qs[128 * 64];
    __shared__ ushort_t ks[128 * 64];
    const int t = threadIdx.x;
    const int wv = t >> 6, ln = t & 63;
    const int wr = wv >> 1, wc = wv & 1;      // wave tile: rows wr*64, cols wc*64
    const int l15 = ln & 15, lhi = ln >> 4;
    const int m0 = blockIdx.x * 128;
    const int split = blockIdx.y;

    // staging constants: wave wv stages tokens [wv*32, wv*32+32) of both tiles
    const int srow = wv * 32;
    const int lr = ln >> 3;          // token within 8-group (0..7)
    const int lc = ln & 7;           // chunk (0..7)
    const int swz = lc ^ lr;         // pre-swizzled source chunk

    float rm[4][4], rl[4][4], ra[4][4];
#pragma unroll
    for (int a = 0; a < 4; ++a)
#pragma unroll
        for (int b = 0; b < 4; ++b) { rm[a][b] = -INFINITY; rl[a][b] = 0.f; ra[a][b] = 0.f; }

    for (int nt = split; nt < NTILES; nt += NSPLIT) {
        const int n0 = nt * 128;
        f32x4 acc[4][4];
#pragma unroll
        for (int a = 0; a < 4; ++a)
#pragma unroll
            for (int b = 0; b < 4; ++b) acc[a][b] = (f32x4)(0.f);

        for (int kk = 0; kk < DD; kk += 64) {
            __syncthreads();
#pragma unroll
            for (int i = 0; i < 4; ++i) {
                const int tok = srow + i * 8 + lr;
                const ushort_t* gq = qb + (size_t)(m0 + tok) * DD + kk + (swz << 3);
                const ushort_t* gk = kb + (size_t)(n0 + tok) * DD + kk + (swz << 3);
                gload_lds16(gq, qs + (srow + i * 8) * 64);
                gload_lds16(gk, ks + (srow + i * 8) * 64);
            }
            __syncthreads();
#pragma unroll
            for (int kp = 0; kp < 2; ++kp) {
                short8 af[4], bf_[4];
#pragma unroll
                for (int mi = 0; mi < 4; ++mi) {
                    int r = wr * 64 + mi * 16 + l15;
                    int c = (kp * 4 + lhi) ^ (r & 7);
                    af[mi] = *(const short8*)(qs + r * 64 + c * 8);
                }
#pragma unroll
                for (int ni = 0; ni < 4; ++ni) {
                    int r = wc * 64 + ni * 16 + l15;
                    int c = (kp * 4 + lhi) ^ (r & 7);
                    bf_[ni] = *(const short8*)(ks + r * 64 + c * 8);
                }
#pragma unroll
                for (int mi = 0; mi < 4; ++mi)
#pragma unroll
                    for (int ni = 0; ni < 4; ++ni)
                        acc[mi][ni] = __builtin_amdgcn_mfma_f32_16x16x32_bf16(
                            af[mi], bf_[ni], acc[mi][ni], 0, 0, 0);
            }
        }
        // online softmax update; score row = wr*64+mi*16+lhi*4+r, col = wc*64+ni*16+l15
        float vv[4];
#pragma unroll
        for (int ni = 0; ni < 4; ++ni) vv[ni] = vsc[n0 + wc * 64 + ni * 16 + l15];
#pragma unroll
        for (int mi = 0; mi < 4; ++mi) {
#pragma unroll
            for (int r = 0; r < 4; ++r) {
                float mx = fmaxf(fmaxf(acc[mi][0][r], acc[mi][1][r]),
                                 fmaxf(acc[mi][2][r], acc[mi][3][r]));
                mx = fmaxf(mx, __shfl_xor(mx, 1));
                mx = fmaxf(mx, __shfl_xor(mx, 2));
                mx = fmaxf(mx, __shfl_xor(mx, 4));
                mx = fmaxf(mx, __shfl_xor(mx, 8));
                const float mnew = fmaxf(rm[mi][r], mx);
                float sp = 0.f, sv = 0.f;
#pragma unroll
                for (int ni = 0; ni < 4; ++ni) {
                    float p = __expf(acc[mi][ni][r] - mnew);
                    sp += p; sv += p * vv[ni];
                }
                sp += __shfl_xor(sp, 1); sv += __shfl_xor(sv, 1);
                sp += __shfl_xor(sp, 2); sv += __shfl_xor(sv, 2);
                sp += __shfl_xor(sp, 4); sv += __shfl_xor(sv, 4);
                sp += __shfl_xor(sp, 8); sv += __shfl_xor(sv, 8);
                const float f = __expf(rm[mi][r] - mnew);
                rl[mi][r] = rl[mi][r] * f + sp;
                ra[mi][r] = ra[mi][r] * f + sv;
                rm[mi][r] = mnew;
            }
        }
    }
    // write partials: slab = split*2 + wc
    if (l15 == 0) {
        const size_t slab = (size_t)(split * 2 + wc) * NN;
#pragma unroll
        for (int mi = 0; mi < 4; ++mi)
#pragma unroll
            for (int r = 0; r < 4; ++r) {
                int row = m0 + wr * 64 + mi * 16 + lhi * 4 + r;
                pm[slab + row] = rm[mi][r];
                pl[slab + row] = rl[mi][r];
                pa[slab + row] = ra[mi][r];
            }
    }
}

// ---------------------------------------------------------------------------
// Merge partials, apply head bias + sigmoid.
__global__ void k_comb(const float* __restrict__ pm, const float* __restrict__ pl,
                       const float* __restrict__ pa, const float* __restrict__ cb,
                       float* __restrict__ out) {
    int n = blockIdx.x * 256 + threadIdx.x;
    float gm = -INFINITY;
#pragma unroll
    for (int s = 0; s < NPART; ++s) gm = fmaxf(gm, pm[(size_t)s * NN + n]);
    float l = 0.f, a = 0.f;
#pragma unroll
    for (int s = 0; s < NPART; ++s) {
        float f = __expf(pm[(size_t)s * NN + n] - gm);
        l += pl[(size_t)s * NN + n] * f;
        a += pa[(size_t)s * NN + n] * f;
    }
    float x = a / l + cb[0];
    out[n] = 1.f / (1.f + __expf(-x));
}

// ---------------------------------------------------------------------------
extern "C" void kernel_launch(void* const* d_in, const int* in_sizes, int n_in,
                              void* d_out, int out_size, void* d_ws, size_t ws_size,
                              hipStream_t stream) {
    const int* sig = (const int*)d_in[0];
    const float* rf = (const float*)d_in[1];
    const float* pe = (const float*)d_in[3];
    const float* Wq = (const float*)d_in[4];
    const float* bq = (const float*)d_in[5];
    const float* Wk = (const float*)d_in[6];
    const float* bk = (const float*)d_in[7];
    const float* Wv = (const float*)d_in[8];
    const float* bv = (const float*)d_in[9];
    const float* cw = (const float*)d_in[10];
    const float* cb = (const float*)d_in[11];
    float* out = (float*)d_out;

    ushort_t* qb = (ushort_t*)d_ws;                  // NN*DD bf16
    ushort_t* kb = qb + (size_t)NN * DD;             // NN*DD bf16
    float* u = (float*)(kb + (size_t)NN * DD);       // 1024
    float* cptr = u + 1024;
    float* vsc = u + 1024 + 16;                      // NN
    float* pm = vsc + NN;                            // NPART*NN
    float* pl = pm + (size_t)NPART * NN;
    float* pa = pl + (size_t)NPART * NN;

    k_u<<<DD / 256, 256, 0, stream>>>(Wv, cw, bv, u, cptr);
    k_vsc<<<NN / 256, 256, 0, stream>>>(rf, u, cptr, vsc);
    k_proj<true><<<dim3(98, 8), 256, 0, stream>>>(Wq, bq, rf, sig, pe, qb, 0.03125f);
    k_proj<false><<<dim3(98, 8), 256, 0, stream>>>(Wk, bk, rf, sig, pe, kb, 1.0f);
    k_attn<<<dim3(98, NSPLIT), 256, 0, stream>>>(qb, kb, vsc, pm, pl, pa);
    k_comb<<<NN / 256, 256, 0, stream>>>(pm, pl, pa, cb, out);
}

// Round 3
// 569.258 us; speedup vs baseline: 9.8663x; 2.3142x over previous
//
#include <hip/hip_runtime.h>
#include <math.h>

// SimilarityModel: seg = sigmoid( softmax(QK^T/32) @ v + c + cb ), v = rf·u scalar per token.
// Round 3: projections moved to bf16 MFMA; prep pass builds bf16 token-major x.

#define DD 1024
#define NN 12544
#define NSPLIT 10
#define NPART  20   // NSPLIT * 2 column-half waves
#define NTILES 98   // NN / 128

typedef __attribute__((ext_vector_type(8))) short short8;
typedef __attribute__((ext_vector_type(4))) float f32x4;
typedef __attribute__((ext_vector_type(4))) unsigned short ushort4_t;
typedef unsigned short ushort_t;
typedef unsigned int uint32;

__device__ __forceinline__ ushort_t f2bf(float f) {
    union { float f; uint32 u; } v; v.f = f;
    uint32 u = v.u + 0x7FFF + ((v.u >> 16) & 1);   // RNE
    return (ushort_t)(u >> 16);
}

__device__ __forceinline__ void gload_lds16(const void* g, void* l) {
    __builtin_amdgcn_global_load_lds((const __attribute__((address_space(1))) uint32*)g,
                                     (__attribute__((address_space(3))) uint32*)l, 16, 0, 0);
}

// ---------------------------------------------------------------------------
// u[k] += sum_{d in slice} Wv[d,k]*cw[d]; blocks (0,y) also reduce c = bv·cw.
// u and cptr must be zeroed before launch.
__global__ void k_u(const float* __restrict__ Wv, const float* __restrict__ cw,
                    const float* __restrict__ bv, float* __restrict__ u,
                    float* __restrict__ cptr) {
    const int t = threadIdx.x;
    const int k = blockIdx.x * 256 + t;
    const int d0 = blockIdx.y * 64;
    float acc = 0.f;
#pragma unroll 16
    for (int i = 0; i < 64; ++i) acc += Wv[(size_t)(d0 + i) * DD + k] * cw[d0 + i];
    atomicAdd(&u[k], acc);
    if (blockIdx.x == 0 && t < 64) {
        float ca = bv[d0 + t] * cw[d0 + t];
        for (int off = 32; off > 0; off >>= 1) ca += __shfl_down(ca, off);
        if (t == 0) atomicAdd(cptr, ca);
    }
}

// ---------------------------------------------------------------------------
// One pass over rf: produce xo (N,D) bf16, xa = rf+pe[sig] (N,D) bf16,
// and vsc[n] = sum_d rf[d,n]*u[d]. 64 tokens per block.
__global__ __launch_bounds__(256)
void k_prep(const float* __restrict__ rf, const int* __restrict__ sig,
            const float* __restrict__ pe, const float* __restrict__ u,
            ushort_t* __restrict__ xo, ushort_t* __restrict__ xa,
            float* __restrict__ vsc) {
    __shared__ ushort_t so[64][136];
    __shared__ ushort_t sa[64][136];
    __shared__ float pel[5 * 128];
    __shared__ float ul[128];
    __shared__ int sigl[64];
    __shared__ f32x4 red[16][16];
    const int t = threadIdx.x;
    const int n0 = blockIdx.x * 64;
    if (t < 64) sigl[t] = sig[n0 + t];
    __syncthreads();
    const int dl = t >> 4, tg = t & 15;
    const int sg[4] = {sigl[tg * 4], sigl[tg * 4 + 1], sigl[tg * 4 + 2], sigl[tg * 4 + 3]};
    const int tok = t >> 2, part = t & 3;
    f32x4 vacc = (f32x4)(0.f);

    for (int c = 0; c < 8; ++c) {
        const int d0 = c * 128;
        for (int i = t; i < 640; i += 256) pel[i] = pe[(i >> 7) * DD + d0 + (i & 127)];
        if (t < 128) ul[t] = u[d0 + t];
        __syncthreads();
#pragma unroll
        for (int s = 0; s < 8; ++s) {
            const int dli = s * 16 + dl;
            const f32x4 x = *(const f32x4*)&rf[(size_t)(d0 + dli) * NN + n0 + tg * 4];
            vacc += x * ul[dli];
            ushort_t oo[4], aa[4];
#pragma unroll
            for (int j = 0; j < 4; ++j) {
                oo[j] = f2bf(x[j]);
                aa[j] = f2bf(x[j] + pel[sg[j] * 128 + dli]);
            }
#pragma unroll
            for (int j = 0; j < 4; ++j) {
                so[tg * 4 + j][dli] = oo[j];
                sa[tg * 4 + j][dli] = aa[j];
            }
        }
        __syncthreads();
#pragma unroll
        for (int i = 0; i < 4; ++i) {
            const int off = part * 32 + i * 8;
            *(short8*)&xo[(size_t)(n0 + tok) * DD + d0 + off] = *(const short8*)&so[tok][off];
            *(short8*)&xa[(size_t)(n0 + tok) * DD + d0 + off] = *(const short8*)&sa[tok][off];
        }
        __syncthreads();
    }
    red[dl][tg] = vacc;
    __syncthreads();
    if (t < 64) {
        float s = 0.f;
#pragma unroll
        for (int i = 0; i < 16; ++i) s += ((const float*)&red[i][t >> 2])[t & 3];
        vsc[n0 + t] = s;
    }
}

// ---------------------------------------------------------------------------
// Cast Wq / Wk to bf16.
__global__ void k_wcast(const float* __restrict__ Wq, const float* __restrict__ Wk,
                        ushort_t* __restrict__ wqb, ushort_t* __restrict__ wkb) {
    const int idx = (blockIdx.x * 256 + threadIdx.x) * 8;
    const float* src = blockIdx.y ? Wk : Wq;
    ushort_t* dst = blockIdx.y ? wkb : wqb;
    f32x4 a = *(const f32x4*)&src[idx];
    f32x4 b = *(const f32x4*)&src[idx + 4];
    short8 o;
#pragma unroll
    for (int j = 0; j < 4; ++j) { o[j] = (short)f2bf(a[j]); o[4 + j] = (short)f2bf(b[j]); }
    *(short8*)&dst[idx] = o;
}

// ---------------------------------------------------------------------------
// Projection GEMM: out[n, d'] = bf16( scale*( sum_d x[n,d]*W[d',d] + bias[d'] ) ).
// A = W rows (d'), B = x rows (tokens) -> C[d'(lhi*4+r), token(l15)], so each
// lane packs 4 consecutive d' into one 8B store.
__global__ __launch_bounds__(256, 2)
void k_pgemm(const ushort_t* __restrict__ xb, const ushort_t* __restrict__ wb,
             const float* __restrict__ bias, float scale, ushort_t* __restrict__ outb) {
    __shared__ ushort_t as_[128 * 64];
    __shared__ ushort_t bs_[128 * 64];
    const int t = threadIdx.x;
    const int wv = t >> 6, ln = t & 63;
    const int wr = wv >> 1, wc = wv & 1;
    const int l15 = ln & 15, lhi = ln >> 4;
    const int n0 = blockIdx.x * 128;   // tokens
    const int m0 = blockIdx.y * 128;   // d'
    const int srow = wv * 32;
    const int lr = ln >> 3, lc = ln & 7;
    const int swz = lc ^ lr;

    f32x4 acc[4][4];
#pragma unroll
    for (int a = 0; a < 4; ++a)
#pragma unroll
        for (int b = 0; b < 4; ++b) acc[a][b] = (f32x4)(0.f);

    for (int kk = 0; kk < DD; kk += 64) {
        __syncthreads();
#pragma unroll
        for (int i = 0; i < 4; ++i) {
            const int tok = srow + i * 8 + lr;
            gload_lds16(wb + (size_t)(m0 + tok) * DD + kk + (swz << 3), as_ + (srow + i * 8) * 64);
            gload_lds16(xb + (size_t)(n0 + tok) * DD + kk + (swz << 3), bs_ + (srow + i * 8) * 64);
        }
        __syncthreads();
#pragma unroll
        for (int kp = 0; kp < 2; ++kp) {
            short8 af[4], bf_[4];
#pragma unroll
            for (int mi = 0; mi < 4; ++mi) {
                int r = wr * 64 + mi * 16 + l15;
                int cch = (kp * 4 + lhi) ^ (r & 7);
                af[mi] = *(const short8*)(as_ + r * 64 + cch * 8);
            }
#pragma unroll
            for (int ni = 0; ni < 4; ++ni) {
                int r = wc * 64 + ni * 16 + l15;
                int cch = (kp * 4 + lhi) ^ (r & 7);
                bf_[ni] = *(const short8*)(bs_ + r * 64 + cch * 8);
            }
#pragma unroll
            for (int mi = 0; mi < 4; ++mi)
#pragma unroll
                for (int ni = 0; ni < 4; ++ni)
                    acc[mi][ni] = __builtin_amdgcn_mfma_f32_16x16x32_bf16(
                        af[mi], bf_[ni], acc[mi][ni], 0, 0, 0);
        }
    }
    float bb[4][4];
#pragma unroll
    for (int mi = 0; mi < 4; ++mi) {
        f32x4 b4 = *(const f32x4*)&bias[m0 + wr * 64 + mi * 16 + lhi * 4];
#pragma unroll
        for (int r = 0; r < 4; ++r) bb[mi][r] = b4[r];
    }
#pragma unroll
    for (int mi = 0; mi < 4; ++mi)
#pragma unroll
        for (int ni = 0; ni < 4; ++ni) {
            ushort4_t o;
#pragma unroll
            for (int r = 0; r < 4; ++r) o[r] = f2bf((acc[mi][ni][r] + bb[mi][r]) * scale);
            *(ushort4_t*)&outb[(size_t)(n0 + wc * 64 + ni * 16 + l15) * DD +
                               m0 + wr * 64 + mi * 16 + lhi * 4] = o;
        }
}

// ---------------------------------------------------------------------------
// Fused MFMA scores + online softmax + weighted scalar-V sum (unchanged).
__global__ __launch_bounds__(256, 2)
void k_attn(const ushort_t* __restrict__ qb, const ushort_t* __restrict__ kb,
            const float* __restrict__ vsc, float* __restrict__ pm,
            float* __restrict__ pl, float* __restrict__ pa) {
    __shared__ ushort_t qs[128 * 64];
    __shared__ ushort_t ks[128 * 64];
    const int t = threadIdx.x;
    const int wv = t >> 6, ln = t & 63;
    const int wr = wv >> 1, wc = wv & 1;
    const int l15 = ln & 15, lhi = ln >> 4;
    const int m0 = blockIdx.x * 128;
    const int split = blockIdx.y;
    const int srow = wv * 32;
    const int lr = ln >> 3, lc = ln & 7;
    const int swz = lc ^ lr;

    float rm[4][4], rl[4][4], ra[4][4];
#pragma unroll
    for (int a = 0; a < 4; ++a)
#pragma unroll
        for (int b = 0; b < 4; ++b) { rm[a][b] = -INFINITY; rl[a][b] = 0.f; ra[a][b] = 0.f; }

    for (int nt = split; nt < NTILES; nt += NSPLIT) {
        const int n0 = nt * 128;
        f32x4 acc[4][4];
#pragma unroll
        for (int a = 0; a < 4; ++a)
#pragma unroll
            for (int b = 0; b < 4; ++b) acc[a][b] = (f32x4)(0.f);

        for (int kk = 0; kk < DD; kk += 64) {
            __syncthreads();
#pragma unroll
            for (int i = 0; i < 4; ++i) {
                const int tok = srow + i * 8 + lr;
                gload_lds16(qb + (size_t)(m0 + tok) * DD + kk + (swz << 3), qs + (srow + i * 8) * 64);
                gload_lds16(kb + (size_t)(n0 + tok) * DD + kk + (swz << 3), ks + (srow + i * 8) * 64);
            }
            __syncthreads();
#pragma unroll
            for (int kp = 0; kp < 2; ++kp) {
                short8 af[4], bf_[4];
#pragma unroll
                for (int mi = 0; mi < 4; ++mi) {
                    int r = wr * 64 + mi * 16 + l15;
                    int cch = (kp * 4 + lhi) ^ (r & 7);
                    af[mi] = *(const short8*)(qs + r * 64 + cch * 8);
                }
#pragma unroll
                for (int ni = 0; ni < 4; ++ni) {
                    int r = wc * 64 + ni * 16 + l15;
                    int cch = (kp * 4 + lhi) ^ (r & 7);
                    bf_[ni] = *(const short8*)(ks + r * 64 + cch * 8);
                }
#pragma unroll
                for (int mi = 0; mi < 4; ++mi)
#pragma unroll
                    for (int ni = 0; ni < 4; ++ni)
                        acc[mi][ni] = __builtin_amdgcn_mfma_f32_16x16x32_bf16(
                            af[mi], bf_[ni], acc[mi][ni], 0, 0, 0);
            }
        }
        float vv[4];
#pragma unroll
        for (int ni = 0; ni < 4; ++ni) vv[ni] = vsc[n0 + wc * 64 + ni * 16 + l15];
#pragma unroll
        for (int mi = 0; mi < 4; ++mi) {
#pragma unroll
            for (int r = 0; r < 4; ++r) {
                float mx = fmaxf(fmaxf(acc[mi][0][r], acc[mi][1][r]),
                                 fmaxf(acc[mi][2][r], acc[mi][3][r]));
                mx = fmaxf(mx, __shfl_xor(mx, 1));
                mx = fmaxf(mx, __shfl_xor(mx, 2));
                mx = fmaxf(mx, __shfl_xor(mx, 4));
                mx = fmaxf(mx, __shfl_xor(mx, 8));
                const float mnew = fmaxf(rm[mi][r], mx);
                float sp = 0.f, sv = 0.f;
#pragma unroll
                for (int ni = 0; ni < 4; ++ni) {
                    float p = __expf(acc[mi][ni][r] - mnew);
                    sp += p; sv += p * vv[ni];
                }
                sp += __shfl_xor(sp, 1); sv += __shfl_xor(sv, 1);
                sp += __shfl_xor(sp, 2); sv += __shfl_xor(sv, 2);
                sp += __shfl_xor(sp, 4); sv += __shfl_xor(sv, 4);
                sp += __shfl_xor(sp, 8); sv += __shfl_xor(sv, 8);
                const float f = __expf(rm[mi][r] - mnew);
                rl[mi][r] = rl[mi][r] * f + sp;
                ra[mi][r] = ra[mi][r] * f + sv;
                rm[mi][r] = mnew;
            }
        }
    }
    if (l15 == 0) {
        const size_t slab = (size_t)(split * 2 + wc) * NN;
#pragma unroll
        for (int mi = 0; mi < 4; ++mi)
#pragma unroll
            for (int r = 0; r < 4; ++r) {
                int row = m0 + wr * 64 + mi * 16 + lhi * 4 + r;
                pm[slab + row] = rm[mi][r];
                pl[slab + row] = rl[mi][r];
                pa[slab + row] = ra[mi][r];
            }
    }
}

// ---------------------------------------------------------------------------
// Merge partials; add conv-head constants (c = bv·cw folded here) + sigmoid.
__global__ void k_comb(const float* __restrict__ pm, const float* __restrict__ pl,
                       const float* __restrict__ pa, const float* __restrict__ cptr,
                       const float* __restrict__ cb, float* __restrict__ out) {
    int n = blockIdx.x * 256 + threadIdx.x;
    float gm = -INFINITY;
#pragma unroll
    for (int s = 0; s < NPART; ++s) gm = fmaxf(gm, pm[(size_t)s * NN + n]);
    float l = 0.f, a = 0.f;
#pragma unroll
    for (int s = 0; s < NPART; ++s) {
        float f = __expf(pm[(size_t)s * NN + n] - gm);
        l += pl[(size_t)s * NN + n] * f;
        a += pa[(size_t)s * NN + n] * f;
    }
    float x = a / l + cptr[0] + cb[0];
    out[n] = 1.f / (1.f + __expf(-x));
}

// ---------------------------------------------------------------------------
extern "C" void kernel_launch(void* const* d_in, const int* in_sizes, int n_in,
                              void* d_out, int out_size, void* d_ws, size_t ws_size,
                              hipStream_t stream) {
    const int* sig = (const int*)d_in[0];
    const float* rf = (const float*)d_in[1];
    const float* pe = (const float*)d_in[3];
    const float* Wq = (const float*)d_in[4];
    const float* bq = (const float*)d_in[5];
    const float* Wk = (const float*)d_in[6];
    const float* bk = (const float*)d_in[7];
    const float* Wv = (const float*)d_in[8];
    const float* bv = (const float*)d_in[9];
    const float* cw = (const float*)d_in[10];
    const float* cb = (const float*)d_in[11];
    float* out = (float*)d_out;

    ushort_t* buf0 = (ushort_t*)d_ws;             // xo, later qb
    ushort_t* buf1 = buf0 + (size_t)NN * DD;      // xa
    ushort_t* buf2 = buf1 + (size_t)NN * DD;      // kb
    ushort_t* wqb = buf2 + (size_t)NN * DD;
    ushort_t* wkb = wqb + (size_t)DD * DD;
    float* u = (float*)(wkb + (size_t)DD * DD);   // 1024
    float* cptr = u + 1024;                       // 16 reserved
    float* vsc = u + 1024 + 16;                   // NN
    float* pm = vsc + NN;
    float* pl = pm + (size_t)NPART * NN;
    float* pa = pl + (size_t)NPART * NN;

    hipMemsetAsync(u, 0, (1024 + 16) * sizeof(float), stream);
    k_u<<<dim3(4, 16), 256, 0, stream>>>(Wv, cw, bv, u, cptr);
    k_prep<<<196, 256, 0, stream>>>(rf, sig, pe, u, buf0, buf1, vsc);
    k_wcast<<<dim3(512, 2), 256, 0, stream>>>(Wq, Wk, wqb, wkb);
    k_pgemm<<<dim3(98, 8), 256, 0, stream>>>(buf0, wkb, bk, 1.0f, buf2);      // K
    k_pgemm<<<dim3(98, 8), 256, 0, stream>>>(buf1, wqb, bq, 0.03125f, buf0);  // Q
    k_attn<<<dim3(98, NSPLIT), 256, 0, stream>>>(buf0, buf2, vsc, pm, pl, pa);
    k_comb<<<NN / 256, 256, 0, stream>>>(pm, pl, pa, cptr, cb, out);
}

// Round 4
// 541.472 us; speedup vs baseline: 10.3725x; 1.0513x over previous
//
#include <hip/hip_runtime.h>
#include <math.h>

// SimilarityModel: seg = sigmoid( softmax(QK^T/32) @ v + c + cb ), v = rf·u scalar per token.
// Round 4: k_attn rebuilt as 8-wave 256x256 tile, BK=32 double-buffered single-barrier
// pipeline (T3-min 2-phase), wave tile 64x128, XCD-swizzled grid.

#define DD 1024
#define NN 12544
#define NSPLIT 5
#define NPART  10   // NSPLIT * 2 column-half waves
#define NTILES 49   // NN / 256

typedef __attribute__((ext_vector_type(8))) short short8;
typedef __attribute__((ext_vector_type(4))) float f32x4;
typedef __attribute__((ext_vector_type(4))) unsigned short ushort4_t;
typedef unsigned short ushort_t;
typedef unsigned int uint32;

__device__ __forceinline__ ushort_t f2bf(float f) {
    union { float f; uint32 u; } v; v.f = f;
    uint32 u = v.u + 0x7FFF + ((v.u >> 16) & 1);   // RNE
    return (ushort_t)(u >> 16);
}

__device__ __forceinline__ void gload_lds16(const void* g, void* l) {
    __builtin_amdgcn_global_load_lds((const __attribute__((address_space(1))) uint32*)g,
                                     (__attribute__((address_space(3))) uint32*)l, 16, 0, 0);
}

// ---------------------------------------------------------------------------
// u[k] += sum_{d in slice} Wv[d,k]*cw[d]; blocks (0,y) also reduce c = bv·cw.
__global__ void k_u(const float* __restrict__ Wv, const float* __restrict__ cw,
                    const float* __restrict__ bv, float* __restrict__ u,
                    float* __restrict__ cptr) {
    const int t = threadIdx.x;
    const int k = blockIdx.x * 256 + t;
    const int d0 = blockIdx.y * 64;
    float acc = 0.f;
#pragma unroll 16
    for (int i = 0; i < 64; ++i) acc += Wv[(size_t)(d0 + i) * DD + k] * cw[d0 + i];
    atomicAdd(&u[k], acc);
    if (blockIdx.x == 0 && t < 64) {
        float ca = bv[d0 + t] * cw[d0 + t];
        for (int off = 32; off > 0; off >>= 1) ca += __shfl_down(ca, off);
        if (t == 0) atomicAdd(cptr, ca);
    }
}

// ---------------------------------------------------------------------------
// One pass over rf: produce xo (N,D) bf16, xa = rf+pe[sig] (N,D) bf16,
// and vsc[n] = sum_d rf[d,n]*u[d]. 64 tokens per block.
__global__ __launch_bounds__(256)
void k_prep(const float* __restrict__ rf, const int* __restrict__ sig,
            const float* __restrict__ pe, const float* __restrict__ u,
            ushort_t* __restrict__ xo, ushort_t* __restrict__ xa,
            float* __restrict__ vsc) {
    __shared__ ushort_t so[64][136];
    __shared__ ushort_t sa[64][136];
    __shared__ float pel[5 * 128];
    __shared__ float ul[128];
    __shared__ int sigl[64];
    __shared__ f32x4 red[16][16];
    const int t = threadIdx.x;
    const int n0 = blockIdx.x * 64;
    if (t < 64) sigl[t] = sig[n0 + t];
    __syncthreads();
    const int dl = t >> 4, tg = t & 15;
    const int sg[4] = {sigl[tg * 4], sigl[tg * 4 + 1], sigl[tg * 4 + 2], sigl[tg * 4 + 3]};
    const int tok = t >> 2, part = t & 3;
    f32x4 vacc = (f32x4)(0.f);

    for (int c = 0; c < 8; ++c) {
        const int d0 = c * 128;
        for (int i = t; i < 640; i += 256) pel[i] = pe[(i >> 7) * DD + d0 + (i & 127)];
        if (t < 128) ul[t] = u[d0 + t];
        __syncthreads();
#pragma unroll
        for (int s = 0; s < 8; ++s) {
            const int dli = s * 16 + dl;
            const f32x4 x = *(const f32x4*)&rf[(size_t)(d0 + dli) * NN + n0 + tg * 4];
            vacc += x * ul[dli];
            ushort_t oo[4], aa[4];
#pragma unroll
            for (int j = 0; j < 4; ++j) {
                oo[j] = f2bf(x[j]);
                aa[j] = f2bf(x[j] + pel[sg[j] * 128 + dli]);
            }
#pragma unroll
            for (int j = 0; j < 4; ++j) {
                so[tg * 4 + j][dli] = oo[j];
                sa[tg * 4 + j][dli] = aa[j];
            }
        }
        __syncthreads();
#pragma unroll
        for (int i = 0; i < 4; ++i) {
            const int off = part * 32 + i * 8;
            *(short8*)&xo[(size_t)(n0 + tok) * DD + d0 + off] = *(const short8*)&so[tok][off];
            *(short8*)&xa[(size_t)(n0 + tok) * DD + d0 + off] = *(const short8*)&sa[tok][off];
        }
        __syncthreads();
    }
    red[dl][tg] = vacc;
    __syncthreads();
    if (t < 64) {
        float s = 0.f;
#pragma unroll
        for (int i = 0; i < 16; ++i) s += ((const float*)&red[i][t >> 2])[t & 3];
        vsc[n0 + t] = s;
    }
}

// ---------------------------------------------------------------------------
// Cast Wq / Wk to bf16.
__global__ void k_wcast(const float* __restrict__ Wq, const float* __restrict__ Wk,
                        ushort_t* __restrict__ wqb, ushort_t* __restrict__ wkb) {
    const int idx = (blockIdx.x * 256 + threadIdx.x) * 8;
    const float* src = blockIdx.y ? Wk : Wq;
    ushort_t* dst = blockIdx.y ? wkb : wqb;
    f32x4 a = *(const f32x4*)&src[idx];
    f32x4 b = *(const f32x4*)&src[idx + 4];
    short8 o;
#pragma unroll
    for (int j = 0; j < 4; ++j) { o[j] = (short)f2bf(a[j]); o[4 + j] = (short)f2bf(b[j]); }
    *(short8*)&dst[idx] = o;
}

// ---------------------------------------------------------------------------
// Projection GEMM: out[n, d'] = bf16( scale*( sum_d x[n,d]*W[d',d] + bias[d'] ) ).
__global__ __launch_bounds__(256, 2)
void k_pgemm(const ushort_t* __restrict__ xb, const ushort_t* __restrict__ wb,
             const float* __restrict__ bias, float scale, ushort_t* __restrict__ outb) {
    __shared__ ushort_t as_[128 * 64];
    __shared__ ushort_t bs_[128 * 64];
    const int t = threadIdx.x;
    const int wv = t >> 6, ln = t & 63;
    const int wr = wv >> 1, wc = wv & 1;
    const int l15 = ln & 15, lhi = ln >> 4;
    const int n0 = blockIdx.x * 128;   // tokens
    const int m0 = blockIdx.y * 128;   // d'
    const int srow = wv * 32;
    const int lr = ln >> 3, lc = ln & 7;
    const int swz = lc ^ lr;

    f32x4 acc[4][4];
#pragma unroll
    for (int a = 0; a < 4; ++a)
#pragma unroll
        for (int b = 0; b < 4; ++b) acc[a][b] = (f32x4)(0.f);

    for (int kk = 0; kk < DD; kk += 64) {
        __syncthreads();
#pragma unroll
        for (int i = 0; i < 4; ++i) {
            const int tok = srow + i * 8 + lr;
            gload_lds16(wb + (size_t)(m0 + tok) * DD + kk + (swz << 3), as_ + (srow + i * 8) * 64);
            gload_lds16(xb + (size_t)(n0 + tok) * DD + kk + (swz << 3), bs_ + (srow + i * 8) * 64);
        }
        __syncthreads();
#pragma unroll
        for (int kp = 0; kp < 2; ++kp) {
            short8 af[4], bf_[4];
#pragma unroll
            for (int mi = 0; mi < 4; ++mi) {
                int r = wr * 64 + mi * 16 + l15;
                int cch = (kp * 4 + lhi) ^ (r & 7);
                af[mi] = *(const short8*)(as_ + r * 64 + cch * 8);
            }
#pragma unroll
            for (int ni = 0; ni < 4; ++ni) {
                int r = wc * 64 + ni * 16 + l15;
                int cch = (kp * 4 + lhi) ^ (r & 7);
                bf_[ni] = *(const short8*)(bs_ + r * 64 + cch * 8);
            }
#pragma unroll
            for (int mi = 0; mi < 4; ++mi)
#pragma unroll
                for (int ni = 0; ni < 4; ++ni)
                    acc[mi][ni] = __builtin_amdgcn_mfma_f32_16x16x32_bf16(
                        af[mi], bf_[ni], acc[mi][ni], 0, 0, 0);
        }
    }
    float bb[4][4];
#pragma unroll
    for (int mi = 0; mi < 4; ++mi) {
        f32x4 b4 = *(const f32x4*)&bias[m0 + wr * 64 + mi * 16 + lhi * 4];
#pragma unroll
        for (int r = 0; r < 4; ++r) bb[mi][r] = b4[r];
    }
#pragma unroll
    for (int mi = 0; mi < 4; ++mi)
#pragma unroll
        for (int ni = 0; ni < 4; ++ni) {
            ushort4_t o;
#pragma unroll
            for (int r = 0; r < 4; ++r) o[r] = f2bf((acc[mi][ni][r] + bb[mi][r]) * scale);
            *(ushort4_t*)&outb[(size_t)(n0 + wc * 64 + ni * 16 + l15) * DD +
                               m0 + wr * 64 + mi * 16 + lhi * 4] = o;
        }
}

// ---------------------------------------------------------------------------
// Fused MFMA scores + online softmax + weighted scalar-V sum.
// 512 threads = 8 waves (4M x 2N), block tile 256 rows x 256 cols, wave tile 64x128.
// BK=32 double-buffered LDS (64 KiB), one barrier per K-step, stage-ahead pipeline.
__global__ __launch_bounds__(512, 2)
void k_attn(const ushort_t* __restrict__ qb, const ushort_t* __restrict__ kb,
            const float* __restrict__ vsc, float* __restrict__ pm,
            float* __restrict__ pl, float* __restrict__ pa) {
    __shared__ ushort_t As[2][256 * 32];
    __shared__ ushort_t Bs[2][256 * 32];
    const int t = threadIdx.x;
    const int wv = t >> 6, ln = t & 63;
    const int wm = wv >> 1, wn = wv & 1;     // wave tile: rows wm*64, cols wn*128
    const int l15 = ln & 15, lhi = ln >> 4;  // lhi in 0..3 = k-chunk for frags

    // XCD-aware bijective swizzle: 245 blocks, q=30, r=5 -> same-bx splits co-XCD.
    const int g = blockIdx.x;
    const int xcd = g & 7, gq = g >> 3;
    const int L = (xcd < 5) ? xcd * 31 + gq : 155 + (xcd - 5) * 30 + gq;
    const int bx = L / NSPLIT, split = L % NSPLIT;
    const int m0 = bx * 256;

    // staging: wave wv handles segs {2wv, 2wv+1} of A and B (16 rows each)
    const int srow0 = (ln >> 2);   // row within seg
    const int spc = ln & 3;        // phys chunk

    float rm[4][4], rl[4][4], ra[4][4];
#pragma unroll
    for (int a = 0; a < 4; ++a)
#pragma unroll
        for (int b = 0; b < 4; ++b) { rm[a][b] = -INFINITY; rl[a][b] = 0.f; ra[a][b] = 0.f; }

    f32x4 acc[4][8];
#pragma unroll
    for (int a = 0; a < 4; ++a)
#pragma unroll
        for (int b = 0; b < 8; ++b) acc[a][b] = (f32x4)(0.f);

    int cur = 0;
    // prologue: stage (nt=split, kk=0) into buf 0
    {
        const int n0 = split * 256;
#pragma unroll
        for (int s2 = 0; s2 < 2; ++s2) {
            const int seg = wv * 2 + s2;
            const int row = seg * 16 + srow0;
            const int c = spc ^ ((row >> 1) & 3);
            gload_lds16(qb + (size_t)(m0 + row) * DD + c * 8, &As[0][seg * 512]);
            gload_lds16(kb + (size_t)(n0 + row) * DD + c * 8, &Bs[0][seg * 512]);
        }
    }
    __syncthreads();

    for (int nt = split; nt < NTILES; nt += NSPLIT) {
        const int n0 = nt * 256;
        for (int kidx = 0; kidx < 32; ++kidx) {
            // issue next-step stage into other buffer
            int nk = kidx + 1, nnt = nt;
            if (nk == 32) { nk = 0; nnt = nt + NSPLIT; }
            if (nnt < NTILES) {
                const int nn0 = nnt * 256;
                const int kko = nk * 32;
                ushort_t* Ad = &As[cur ^ 1][0];
                ushort_t* Bd = &Bs[cur ^ 1][0];
#pragma unroll
                for (int s2 = 0; s2 < 2; ++s2) {
                    const int seg = wv * 2 + s2;
                    const int row = seg * 16 + srow0;
                    const int c = spc ^ ((row >> 1) & 3);
                    gload_lds16(qb + (size_t)(m0 + row) * DD + kko + c * 8, Ad + seg * 512);
                    gload_lds16(kb + (size_t)(nn0 + row) * DD + kko + c * 8, Bd + seg * 512);
                }
            }
            // fragment reads from current buffer
            const ushort_t* Ab = &As[cur][0];
            const ushort_t* Bb = &Bs[cur][0];
            short8 af[4], bfr[8];
#pragma unroll
            for (int mi = 0; mi < 4; ++mi) {
                const int row = wm * 64 + mi * 16 + l15;
                const int phys = lhi ^ ((row >> 1) & 3);
                af[mi] = *(const short8*)(Ab + row * 32 + phys * 8);
            }
#pragma unroll
            for (int ni = 0; ni < 8; ++ni) {
                const int row = wn * 128 + ni * 16 + l15;
                const int phys = lhi ^ ((row >> 1) & 3);
                bfr[ni] = *(const short8*)(Bb + row * 32 + phys * 8);
            }
            __builtin_amdgcn_s_setprio(1);
#pragma unroll
            for (int ni = 0; ni < 8; ++ni)
#pragma unroll
                for (int mi = 0; mi < 4; ++mi)
                    acc[mi][ni] = __builtin_amdgcn_mfma_f32_16x16x32_bf16(
                        af[mi], bfr[ni], acc[mi][ni], 0, 0, 0);
            __builtin_amdgcn_s_setprio(0);
            __syncthreads();
            cur ^= 1;
        }
        // ---- online softmax epilogue over this 256-col tile ----
        float vv[8];
#pragma unroll
        for (int ni = 0; ni < 8; ++ni) vv[ni] = vsc[n0 + wn * 128 + ni * 16 + l15];
#pragma unroll
        for (int mi = 0; mi < 4; ++mi) {
#pragma unroll
            for (int r = 0; r < 4; ++r) {
                float mx = acc[mi][0][r];
#pragma unroll
                for (int ni = 1; ni < 8; ++ni) mx = fmaxf(mx, acc[mi][ni][r]);
                mx = fmaxf(mx, __shfl_xor(mx, 1));
                mx = fmaxf(mx, __shfl_xor(mx, 2));
                mx = fmaxf(mx, __shfl_xor(mx, 4));
                mx = fmaxf(mx, __shfl_xor(mx, 8));
                const float mnew = fmaxf(rm[mi][r], mx);
                float sp = 0.f, sv = 0.f;
#pragma unroll
                for (int ni = 0; ni < 8; ++ni) {
                    float p = __expf(acc[mi][ni][r] - mnew);
                    sp += p; sv += p * vv[ni];
                }
                sp += __shfl_xor(sp, 1); sv += __shfl_xor(sv, 1);
                sp += __shfl_xor(sp, 2); sv += __shfl_xor(sv, 2);
                sp += __shfl_xor(sp, 4); sv += __shfl_xor(sv, 4);
                sp += __shfl_xor(sp, 8); sv += __shfl_xor(sv, 8);
                const float f = __expf(rm[mi][r] - mnew);
                rl[mi][r] = rl[mi][r] * f + sp;
                ra[mi][r] = ra[mi][r] * f + sv;
                rm[mi][r] = mnew;
            }
        }
#pragma unroll
        for (int a = 0; a < 4; ++a)
#pragma unroll
            for (int b = 0; b < 8; ++b) acc[a][b] = (f32x4)(0.f);
    }
    // write partials: slab = split*2 + wn
    if (l15 == 0) {
        const size_t slab = (size_t)(split * 2 + wn) * NN;
#pragma unroll
        for (int mi = 0; mi < 4; ++mi)
#pragma unroll
            for (int r = 0; r < 4; ++r) {
                int row = m0 + wm * 64 + mi * 16 + lhi * 4 + r;
                pm[slab + row] = rm[mi][r];
                pl[slab + row] = rl[mi][r];
                pa[slab + row] = ra[mi][r];
            }
    }
}

// ---------------------------------------------------------------------------
// Merge partials; add conv-head constants (c = bv·cw folded here) + sigmoid.
__global__ void k_comb(const float* __restrict__ pm, const float* __restrict__ pl,
                       const float* __restrict__ pa, const float* __restrict__ cptr,
                       const float* __restrict__ cb, float* __restrict__ out) {
    int n = blockIdx.x * 256 + threadIdx.x;
    float gm = -INFINITY;
#pragma unroll
    for (int s = 0; s < NPART; ++s) gm = fmaxf(gm, pm[(size_t)s * NN + n]);
    float l = 0.f, a = 0.f;
#pragma unroll
    for (int s = 0; s < NPART; ++s) {
        float f = __expf(pm[(size_t)s * NN + n] - gm);
        l += pl[(size_t)s * NN + n] * f;
        a += pa[(size_t)s * NN + n] * f;
    }
    float x = a / l + cptr[0] + cb[0];
    out[n] = 1.f / (1.f + __expf(-x));
}

// ---------------------------------------------------------------------------
extern "C" void kernel_launch(void* const* d_in, const int* in_sizes, int n_in,
                              void* d_out, int out_size, void* d_ws, size_t ws_size,
                              hipStream_t stream) {
    const int* sig = (const int*)d_in[0];
    const float* rf = (const float*)d_in[1];
    const float* pe = (const float*)d_in[3];
    const float* Wq = (const float*)d_in[4];
    const float* bq = (const float*)d_in[5];
    const float* Wk = (const float*)d_in[6];
    const float* bk = (const float*)d_in[7];
    const float* Wv = (const float*)d_in[8];
    const float* bv = (const float*)d_in[9];
    const float* cw = (const float*)d_in[10];
    const float* cb = (const float*)d_in[11];
    float* out = (float*)d_out;

    ushort_t* buf0 = (ushort_t*)d_ws;             // xo, later qb
    ushort_t* buf1 = buf0 + (size_t)NN * DD;      // xa
    ushort_t* buf2 = buf1 + (size_t)NN * DD;      // kb
    ushort_t* wqb = buf2 + (size_t)NN * DD;
    ushort_t* wkb = wqb + (size_t)DD * DD;
    float* u = (float*)(wkb + (size_t)DD * DD);   // 1024
    float* cptr = u + 1024;                       // 16 reserved
    float* vsc = u + 1024 + 16;                   // NN
    float* pm = vsc + NN;
    float* pl = pm + (size_t)NPART * NN;
    float* pa = pl + (size_t)NPART * NN;

    hipMemsetAsync(u, 0, (1024 + 16) * sizeof(float), stream);
    k_u<<<dim3(4, 16), 256, 0, stream>>>(Wv, cw, bv, u, cptr);
    k_prep<<<196, 256, 0, stream>>>(rf, sig, pe, u, buf0, buf1, vsc);
    k_wcast<<<dim3(512, 2), 256, 0, stream>>>(Wq, Wk, wqb, wkb);
    k_pgemm<<<dim3(98, 8), 256, 0, stream>>>(buf0, wkb, bk, 1.0f, buf2);      // K
    k_pgemm<<<dim3(98, 8), 256, 0, stream>>>(buf1, wqb, bq, 0.03125f, buf0);  // Q
    k_attn<<<245, 512, 0, stream>>>(buf0, buf2, vsc, pm, pl, pa);
    k_comb<<<NN / 256, 256, 0, stream>>>(pm, pl, pa, cptr, cb, out);
}

// Round 5
// 484.264 us; speedup vs baseline: 11.5979x; 1.1181x over previous
//
#include <hip/hip_runtime.h>
#include <math.h>

// SimilarityModel: seg = sigmoid( softmax(QK^T/32) @ v + c + cb ), v = rf·u scalar per token.
// Round 5: k_attn BK=64 pipeline — full-cache-line staging, raw barrier + counted-drain
// (vmcnt(0) amortized over 64-MFMA step), softmax-overlapped next-tile prefetch.

#define DD 1024
#define NN 12544
#define NSPLIT 5
#define NPART  10   // NSPLIT * 2 column-half waves
#define NTILES 49   // NN / 256

typedef __attribute__((ext_vector_type(8))) short short8;
typedef __attribute__((ext_vector_type(4))) float f32x4;
typedef __attribute__((ext_vector_type(4))) unsigned short ushort4_t;
typedef unsigned short ushort_t;
typedef unsigned int uint32;

__device__ __forceinline__ ushort_t f2bf(float f) {
    union { float f; uint32 u; } v; v.f = f;
    uint32 u = v.u + 0x7FFF + ((v.u >> 16) & 1);   // RNE
    return (ushort_t)(u >> 16);
}

__device__ __forceinline__ void gload_lds16(const void* g, void* l) {
    __builtin_amdgcn_global_load_lds((const __attribute__((address_space(1))) uint32*)g,
                                     (__attribute__((address_space(3))) uint32*)l, 16, 0, 0);
}

// ---------------------------------------------------------------------------
// u[k] += sum_{d in slice} Wv[d,k]*cw[d]; blocks (0,y) also reduce c = bv·cw.
__global__ void k_u(const float* __restrict__ Wv, const float* __restrict__ cw,
                    const float* __restrict__ bv, float* __restrict__ u,
                    float* __restrict__ cptr) {
    const int t = threadIdx.x;
    const int k = blockIdx.x * 256 + t;
    const int d0 = blockIdx.y * 64;
    float acc = 0.f;
#pragma unroll 16
    for (int i = 0; i < 64; ++i) acc += Wv[(size_t)(d0 + i) * DD + k] * cw[d0 + i];
    atomicAdd(&u[k], acc);
    if (blockIdx.x == 0 && t < 64) {
        float ca = bv[d0 + t] * cw[d0 + t];
        for (int off = 32; off > 0; off >>= 1) ca += __shfl_down(ca, off);
        if (t == 0) atomicAdd(cptr, ca);
    }
}

// ---------------------------------------------------------------------------
// One pass over rf: produce xo (N,D) bf16, xa = rf+pe[sig] (N,D) bf16,
// and vsc[n] = sum_d rf[d,n]*u[d]. 64 tokens per block.
__global__ __launch_bounds__(256)
void k_prep(const float* __restrict__ rf, const int* __restrict__ sig,
            const float* __restrict__ pe, const float* __restrict__ u,
            ushort_t* __restrict__ xo, ushort_t* __restrict__ xa,
            float* __restrict__ vsc) {
    __shared__ ushort_t so[64][136];
    __shared__ ushort_t sa[64][136];
    __shared__ float pel[5 * 128];
    __shared__ float ul[128];
    __shared__ int sigl[64];
    __shared__ f32x4 red[16][16];
    const int t = threadIdx.x;
    const int n0 = blockIdx.x * 64;
    if (t < 64) sigl[t] = sig[n0 + t];
    __syncthreads();
    const int dl = t >> 4, tg = t & 15;
    const int sg[4] = {sigl[tg * 4], sigl[tg * 4 + 1], sigl[tg * 4 + 2], sigl[tg * 4 + 3]};
    const int tok = t >> 2, part = t & 3;
    f32x4 vacc = (f32x4)(0.f);

    for (int c = 0; c < 8; ++c) {
        const int d0 = c * 128;
        for (int i = t; i < 640; i += 256) pel[i] = pe[(i >> 7) * DD + d0 + (i & 127)];
        if (t < 128) ul[t] = u[d0 + t];
        __syncthreads();
#pragma unroll
        for (int s = 0; s < 8; ++s) {
            const int dli = s * 16 + dl;
            const f32x4 x = *(const f32x4*)&rf[(size_t)(d0 + dli) * NN + n0 + tg * 4];
            vacc += x * ul[dli];
            ushort_t oo[4], aa[4];
#pragma unroll
            for (int j = 0; j < 4; ++j) {
                oo[j] = f2bf(x[j]);
                aa[j] = f2bf(x[j] + pel[sg[j] * 128 + dli]);
            }
#pragma unroll
            for (int j = 0; j < 4; ++j) {
                so[tg * 4 + j][dli] = oo[j];
                sa[tg * 4 + j][dli] = aa[j];
            }
        }
        __syncthreads();
#pragma unroll
        for (int i = 0; i < 4; ++i) {
            const int off = part * 32 + i * 8;
            *(short8*)&xo[(size_t)(n0 + tok) * DD + d0 + off] = *(const short8*)&so[tok][off];
            *(short8*)&xa[(size_t)(n0 + tok) * DD + d0 + off] = *(const short8*)&sa[tok][off];
        }
        __syncthreads();
    }
    red[dl][tg] = vacc;
    __syncthreads();
    if (t < 64) {
        float s = 0.f;
#pragma unroll
        for (int i = 0; i < 16; ++i) s += ((const float*)&red[i][t >> 2])[t & 3];
        vsc[n0 + t] = s;
    }
}

// ---------------------------------------------------------------------------
// Cast Wq / Wk to bf16.
__global__ void k_wcast(const float* __restrict__ Wq, const float* __restrict__ Wk,
                        ushort_t* __restrict__ wqb, ushort_t* __restrict__ wkb) {
    const int idx = (blockIdx.x * 256 + threadIdx.x) * 8;
    const float* src = blockIdx.y ? Wk : Wq;
    ushort_t* dst = blockIdx.y ? wkb : wqb;
    f32x4 a = *(const f32x4*)&src[idx];
    f32x4 b = *(const f32x4*)&src[idx + 4];
    short8 o;
#pragma unroll
    for (int j = 0; j < 4; ++j) { o[j] = (short)f2bf(a[j]); o[4 + j] = (short)f2bf(b[j]); }
    *(short8*)&dst[idx] = o;
}

// ---------------------------------------------------------------------------
// Projection GEMM: out[n, d'] = bf16( scale*( sum_d x[n,d]*W[d',d] + bias[d'] ) ).
__global__ __launch_bounds__(256, 2)
void k_pgemm(const ushort_t* __restrict__ xb, const ushort_t* __restrict__ wb,
             const float* __restrict__ bias, float scale, ushort_t* __restrict__ outb) {
    __shared__ ushort_t as_[128 * 64];
    __shared__ ushort_t bs_[128 * 64];
    const int t = threadIdx.x;
    const int wv = t >> 6, ln = t & 63;
    const int wr = wv >> 1, wc = wv & 1;
    const int l15 = ln & 15, lhi = ln >> 4;
    const int n0 = blockIdx.x * 128;   // tokens
    const int m0 = blockIdx.y * 128;   // d'
    const int srow = wv * 32;
    const int lr = ln >> 3, lc = ln & 7;
    const int swz = lc ^ lr;

    f32x4 acc[4][4];
#pragma unroll
    for (int a = 0; a < 4; ++a)
#pragma unroll
        for (int b = 0; b < 4; ++b) acc[a][b] = (f32x4)(0.f);

    for (int kk = 0; kk < DD; kk += 64) {
        __syncthreads();
#pragma unroll
        for (int i = 0; i < 4; ++i) {
            const int tok = srow + i * 8 + lr;
            gload_lds16(wb + (size_t)(m0 + tok) * DD + kk + (swz << 3), as_ + (srow + i * 8) * 64);
            gload_lds16(xb + (size_t)(n0 + tok) * DD + kk + (swz << 3), bs_ + (srow + i * 8) * 64);
        }
        __syncthreads();
#pragma unroll
        for (int kp = 0; kp < 2; ++kp) {
            short8 af[4], bf_[4];
#pragma unroll
            for (int mi = 0; mi < 4; ++mi) {
                int r = wr * 64 + mi * 16 + l15;
                int cch = (kp * 4 + lhi) ^ (r & 7);
                af[mi] = *(const short8*)(as_ + r * 64 + cch * 8);
            }
#pragma unroll
            for (int ni = 0; ni < 4; ++ni) {
                int r = wc * 64 + ni * 16 + l15;
                int cch = (kp * 4 + lhi) ^ (r & 7);
                bf_[ni] = *(const short8*)(bs_ + r * 64 + cch * 8);
            }
#pragma unroll
            for (int mi = 0; mi < 4; ++mi)
#pragma unroll
                for (int ni = 0; ni < 4; ++ni)
                    acc[mi][ni] = __builtin_amdgcn_mfma_f32_16x16x32_bf16(
                        af[mi], bf_[ni], acc[mi][ni], 0, 0, 0);
        }
    }
    float bb[4][4];
#pragma unroll
    for (int mi = 0; mi < 4; ++mi) {
        f32x4 b4 = *(const f32x4*)&bias[m0 + wr * 64 + mi * 16 + lhi * 4];
#pragma unroll
        for (int r = 0; r < 4; ++r) bb[mi][r] = b4[r];
    }
#pragma unroll
    for (int mi = 0; mi < 4; ++mi)
#pragma unroll
        for (int ni = 0; ni < 4; ++ni) {
            ushort4_t o;
#pragma unroll
            for (int r = 0; r < 4; ++r) o[r] = f2bf((acc[mi][ni][r] + bb[mi][r]) * scale);
            *(ushort4_t*)&outb[(size_t)(n0 + wc * 64 + ni * 16 + l15) * DD +
                               m0 + wr * 64 + mi * 16 + lhi * 4] = o;
        }
}

// ---------------------------------------------------------------------------
// Fused MFMA scores + online softmax + weighted scalar-V sum.
// 512 threads = 8 waves (4M x 2N), block tile 256x256, wave tile 64x128, BK=64.
// LDS: 2 dbuf x (A 32K + B 32K) = 128 KiB. One raw barrier per K-step; all 8
// next-step loads issued at step top; drain amortized over 64 MFMAs. Last step
// of each nt keeps next tile's loads in flight through the softmax epilogue.
__global__ __launch_bounds__(512, 2)
void k_attn(const ushort_t* __restrict__ qb, const ushort_t* __restrict__ kb,
            const float* __restrict__ vsc, float* __restrict__ pm,
            float* __restrict__ pl, float* __restrict__ pa) {
    __shared__ ushort_t As[2][256 * 64];
    __shared__ ushort_t Bs[2][256 * 64];
    const int t = threadIdx.x;
    const int wv = t >> 6, ln = t & 63;
    const int wm = wv >> 1, wn = wv & 1;     // wave tile: rows wm*64, cols wn*128
    const int l15 = ln & 15, lhi = ln >> 4;

    // XCD-aware bijective swizzle: 245 blocks, q=30, r=5 -> same-bx splits co-XCD.
    const int g = blockIdx.x;
    const int xcd = g & 7, gq = g >> 3;
    const int L = (xcd < 5) ? xcd * 31 + gq : 155 + (xcd - 5) * 30 + gq;
    const int bx = L / NSPLIT, split = L % NSPLIT;
    const int m0 = bx * 256;

    // staging coords: block-wide load b covers rows b*64..b*64+63 (8 rows/wave,
    // 128B contiguous per row, source chunk pre-swizzled within the 128B line)
    const int srw = (ln >> 3);        // row within wave's 8-row group
    const int sch = ln & 7;           // chunk within row

    float rm[4][4], rl[4][4], ra[4][4];
#pragma unroll
    for (int a = 0; a < 4; ++a)
#pragma unroll
        for (int b = 0; b < 4; ++b) { rm[a][b] = -INFINITY; rl[a][b] = 0.f; ra[a][b] = 0.f; }

    f32x4 acc[4][8];
#pragma unroll
    for (int a = 0; a < 4; ++a)
#pragma unroll
        for (int b = 0; b < 8; ++b) acc[a][b] = (f32x4)(0.f);

    int cur = 0;
    // prologue: stage (nt=split, kk=0) into buf 0
    {
        const int n0 = split * 256;
#pragma unroll
        for (int b = 0; b < 4; ++b) {
            const int r = b * 64 + wv * 8 + srw;
            const int soff = (sch ^ (r & 7)) << 3;
            gload_lds16(qb + (size_t)(m0 + r) * DD + soff, &As[0][(b * 64 + wv * 8) * 64]);
            gload_lds16(kb + (size_t)(n0 + r) * DD + soff, &Bs[0][(b * 64 + wv * 8) * 64]);
        }
    }
    asm volatile("s_waitcnt vmcnt(0)" ::: "memory");
    __builtin_amdgcn_s_barrier();

    for (int nt = split; nt < NTILES; nt += NSPLIT) {
        const int n0 = nt * 256;
        for (int kidx = 0; kidx < 16; ++kidx) {
            // issue all 8 next-step stages into the other buffer
            int nk = kidx + 1, nnt = nt;
            if (nk == 16) { nk = 0; nnt = nt + NSPLIT; }
            if (nnt < NTILES) {
                const int kko = nk * 64;
                const int nn0 = nnt * 256;
                ushort_t* Ad = &As[cur ^ 1][0];
                ushort_t* Bd = &Bs[cur ^ 1][0];
#pragma unroll
                for (int b = 0; b < 4; ++b) {
                    const int r = b * 64 + wv * 8 + srw;
                    const int soff = kko + ((sch ^ (r & 7)) << 3);
                    gload_lds16(qb + (size_t)(m0 + r) * DD + soff, Ad + (b * 64 + wv * 8) * 64);
                    gload_lds16(kb + (size_t)(nn0 + r) * DD + soff, Bd + (b * 64 + wv * 8) * 64);
                }
            }
            // compute from current buffer: 2 kp sub-steps x 32 MFMA
            const ushort_t* Ab = &As[cur][0];
            const ushort_t* Bb = &Bs[cur][0];
#pragma unroll
            for (int kp = 0; kp < 2; ++kp) {
                short8 af[4], bfr[8];
#pragma unroll
                for (int mi = 0; mi < 4; ++mi) {
                    const int r = wm * 64 + mi * 16 + l15;
                    const int c = (kp * 4 + lhi) ^ (r & 7);
                    af[mi] = *(const short8*)(Ab + r * 64 + c * 8);
                }
#pragma unroll
                for (int ni = 0; ni < 8; ++ni) {
                    const int r = wn * 128 + ni * 16 + l15;
                    const int c = (kp * 4 + lhi) ^ (r & 7);
                    bfr[ni] = *(const short8*)(Bb + r * 64 + c * 8);
                }
                __builtin_amdgcn_s_setprio(1);
#pragma unroll
                for (int ni = 0; ni < 8; ++ni)
#pragma unroll
                    for (int mi = 0; mi < 4; ++mi)
                        acc[mi][ni] = __builtin_amdgcn_mfma_f32_16x16x32_bf16(
                            af[mi], bfr[ni], acc[mi][ni], 0, 0, 0);
                __builtin_amdgcn_s_setprio(0);
            }
            if (kidx == 15) {
                // ---- online softmax epilogue (next tile's loads stay in flight) ----
                float vv[8];
#pragma unroll
                for (int ni = 0; ni < 8; ++ni) vv[ni] = vsc[n0 + wn * 128 + ni * 16 + l15];
#pragma unroll
                for (int mi = 0; mi < 4; ++mi) {
#pragma unroll
                    for (int r = 0; r < 4; ++r) {
                        float mx = acc[mi][0][r];
#pragma unroll
                        for (int ni = 1; ni < 8; ++ni) mx = fmaxf(mx, acc[mi][ni][r]);
                        mx = fmaxf(mx, __shfl_xor(mx, 1));
                        mx = fmaxf(mx, __shfl_xor(mx, 2));
                        mx = fmaxf(mx, __shfl_xor(mx, 4));
                        mx = fmaxf(mx, __shfl_xor(mx, 8));
                        const float mnew = fmaxf(rm[mi][r], mx);
                        float sp = 0.f, sv = 0.f;
#pragma unroll
                        for (int ni = 0; ni < 8; ++ni) {
                            float p = __expf(acc[mi][ni][r] - mnew);
                            sp += p; sv += p * vv[ni];
                        }
                        sp += __shfl_xor(sp, 1); sv += __shfl_xor(sv, 1);
                        sp += __shfl_xor(sp, 2); sv += __shfl_xor(sv, 2);
                        sp += __shfl_xor(sp, 4); sv += __shfl_xor(sv, 4);
                        sp += __shfl_xor(sp, 8); sv += __shfl_xor(sv, 8);
                        const float f = __expf(rm[mi][r] - mnew);
                        rl[mi][r] = rl[mi][r] * f + sp;
                        ra[mi][r] = ra[mi][r] * f + sv;
                        rm[mi][r] = mnew;
                    }
                }
#pragma unroll
                for (int a = 0; a < 4; ++a)
#pragma unroll
                    for (int b = 0; b < 8; ++b) acc[a][b] = (f32x4)(0.f);
            }
            asm volatile("s_waitcnt vmcnt(0)" ::: "memory");
            __builtin_amdgcn_s_barrier();
            cur ^= 1;
        }
    }
    // write partials: slab = split*2 + wn
    if (l15 == 0) {
        const size_t slab = (size_t)(split * 2 + wn) * NN;
#pragma unroll
        for (int mi = 0; mi < 4; ++mi)
#pragma unroll
            for (int r = 0; r < 4; ++r) {
                int row = m0 + wm * 64 + mi * 16 + lhi * 4 + r;
                pm[slab + row] = rm[mi][r];
                pl[slab + row] = rl[mi][r];
                pa[slab + row] = ra[mi][r];
            }
    }
}

// ---------------------------------------------------------------------------
// Merge partials; add conv-head constants (c = bv·cw folded here) + sigmoid.
__global__ void k_comb(const float* __restrict__ pm, const float* __restrict__ pl,
                       const float* __restrict__ pa, const float* __restrict__ cptr,
                       const float* __restrict__ cb, float* __restrict__ out) {
    int n = blockIdx.x * 256 + threadIdx.x;
    float gm = -INFINITY;
#pragma unroll
    for (int s = 0; s < NPART; ++s) gm = fmaxf(gm, pm[(size_t)s * NN + n]);
    float l = 0.f, a = 0.f;
#pragma unroll
    for (int s = 0; s < NPART; ++s) {
        float f = __expf(pm[(size_t)s * NN + n] - gm);
        l += pl[(size_t)s * NN + n] * f;
        a += pa[(size_t)s * NN + n] * f;
    }
    float x = a / l + cptr[0] + cb[0];
    out[n] = 1.f / (1.f + __expf(-x));
}

// ---------------------------------------------------------------------------
extern "C" void kernel_launch(void* const* d_in, const int* in_sizes, int n_in,
                              void* d_out, int out_size, void* d_ws, size_t ws_size,
                              hipStream_t stream) {
    const int* sig = (const int*)d_in[0];
    const float* rf = (const float*)d_in[1];
    const float* pe = (const float*)d_in[3];
    const float* Wq = (const float*)d_in[4];
    const float* bq = (const float*)d_in[5];
    const float* Wk = (const float*)d_in[6];
    const float* bk = (const float*)d_in[7];
    const float* Wv = (const float*)d_in[8];
    const float* bv = (const float*)d_in[9];
    const float* cw = (const float*)d_in[10];
    const float* cb = (const float*)d_in[11];
    float* out = (float*)d_out;

    ushort_t* buf0 = (ushort_t*)d_ws;             // xo, later qb
    ushort_t* buf1 = buf0 + (size_t)NN * DD;      // xa
    ushort_t* buf2 = buf1 + (size_t)NN * DD;      // kb
    ushort_t* wqb = buf2 + (size_t)NN * DD;
    ushort_t* wkb = wqb + (size_t)DD * DD;
    float* u = (float*)(wkb + (size_t)DD * DD);   // 1024
    float* cptr = u + 1024;                       // 16 reserved
    float* vsc = u + 1024 + 16;                   // NN
    float* pm = vsc + NN;
    float* pl = pm + (size_t)NPART * NN;
    float* pa = pl + (size_t)NPART * NN;

    hipMemsetAsync(u, 0, (1024 + 16) * sizeof(float), stream);
    k_u<<<dim3(4, 16), 256, 0, stream>>>(Wv, cw, bv, u, cptr);
    k_prep<<<196, 256, 0, stream>>>(rf, sig, pe, u, buf0, buf1, vsc);
    k_wcast<<<dim3(512, 2), 256, 0, stream>>>(Wq, Wk, wqb, wkb);
    k_pgemm<<<dim3(98, 8), 256, 0, stream>>>(buf0, wkb, bk, 1.0f, buf2);      // K
    k_pgemm<<<dim3(98, 8), 256, 0, stream>>>(buf1, wqb, bq, 0.03125f, buf0);  // Q
    k_attn<<<245, 512, 0, stream>>>(buf0, buf2, vsc, pm, pl, pa);
    k_comb<<<NN / 256, 256, 0, stream>>>(pm, pl, pa, cptr, cb, out);
}